// Round 13
// baseline (1052.158 us; speedup 1.0000x reference)
//
#include <hip/hip_runtime.h>
#include <hip/hip_bf16.h>
#include <stdint.h>

#define EN    8
#define DIN   512
#define HID   1024
#define BATCH 16384
#define LN_EPS 1e-5f

typedef __bf16   bf16x8 __attribute__((ext_vector_type(8)));
typedef float    f32x4  __attribute__((ext_vector_type(4)));
typedef uint16_t u16x4  __attribute__((ext_vector_type(4)));
typedef float    fl4    __attribute__((ext_vector_type(4)));

__device__ __forceinline__ uint16_t f2bf(float f) {
  uint32_t x = __builtin_bit_cast(uint32_t, f);
  uint32_t r = (x + 0x7fffu + ((x >> 16) & 1u)) >> 16;  // RNE
  return (uint16_t)r;
}

__device__ __forceinline__ void gload16(const uint16_t* g, char* lds_d) {
  __builtin_amdgcn_global_load_lds(
      (const __attribute__((address_space(1))) uint32_t*)g,
      (__attribute__((address_space(3))) uint32_t*)lds_d, 16, 0, 0);
}

__device__ __forceinline__ f32x4 MF(bf16x8 a, bf16x8 b, f32x4 c) {
  return __builtin_amdgcn_mfma_f32_16x16x32_bf16(a, b, c, 0, 0, 0);
}

// ---------------- conversion: fp32 -> bf16 ----------------
__global__ __launch_bounds__(256) void cvt_bf16(const float* __restrict__ src,
                                                uint16_t* __restrict__ dst, long n) {
  long i = ((long)blockIdx.x * 256 + threadIdx.x) * 4;
  if (i >= n) return;
  fl4 v = *(const fl4*)(src + i);
  u16x4 o;
  #pragma unroll
  for (int j = 0; j < 4; ++j) o[j] = f2bf(v[j]);
  *(u16x4*)(dst + i) = o;
}

// ---------------- transpose + convert: [E][R][C] fp32 -> [E][C][R] bf16 ----------------
__global__ __launch_bounds__(256) void transpose_cvt(const float* __restrict__ src,
                                                     uint16_t* __restrict__ dst,
                                                     int R, int C) {
  __shared__ float tile[32][33];
  const int e = blockIdx.z;
  const int c0 = blockIdx.x * 32;
  const int r0 = blockIdx.y * 32;
  const int tx = threadIdx.x & 31, ty = threadIdx.x >> 5;
  const float* s = src + (size_t)e * R * C;
  uint16_t*    d = dst + (size_t)e * R * C;
  #pragma unroll
  for (int i = 0; i < 32; i += 8)
    tile[ty + i][tx] = s[(size_t)(r0 + ty + i) * C + (c0 + tx)];
  __syncthreads();
  #pragma unroll
  for (int i = 0; i < 32; i += 8)
    d[(size_t)(c0 + ty + i) * R + (r0 + tx)] = f2bf(tile[tx][ty + i]);
}

// ================== FULL-ROW fused GEMM core (BM=64, BN=HID=1024, BK=32) ==================
// Each block computes 64 COMPLETE output rows for one ensemble member e ->
// LayerNorm can be fused in the epilogue.  512 thr = 8 waves; wave wv owns cols
// wv*128..+127 (mi=4 x ni=8 frags, acc 128 VGPR).  B (weights^T [HID][K]) double-
// buffered in LDS 2x64KB (the proven 131072 size); rows packed in pairs into 128B
// lines with the R12-verified 8-unit XOR swizzle (0 conflicts, HW-validated).
// A fragments are loaded GLOBAL->REGISTER (4 KB/kt working set, L1-resident; off
// the LDS pipe).  One vmcnt(0)+barrier per kt, issued ~1240 MFMA-cycles after the
// stage -> latency hidden.  EPI=0: LN+ReLU+store h1n.  EPI=1: LN+ReLU+dot(W3)+qs.
template <int EPI>
__global__ __launch_bounds__(512, 2) void gemm_fused(
    const uint16_t* __restrict__ A, size_t a_estride,
    const uint16_t* __restrict__ Bt,      // [E][HID][K]
    const float*    __restrict__ bias,    // [E][HID]
    const float*    __restrict__ g,       // [E][HID]
    const float*    __restrict__ be,      // [E][HID]
    const float*    __restrict__ W3,      // [E][HID]   (EPI=1)
    const float*    __restrict__ b3,      // [E]        (EPI=1)
    uint16_t*       __restrict__ H,       // [E][CB][HID] (EPI=0)
    float*          __restrict__ out,     // q/qs buffer  (EPI=1)
    int CBrows, int b0, int K) {
  __shared__ __attribute__((aligned(16))) char lds[131072];   // 2 x 64KB B slots
  const int tid = threadIdx.x;
  const int e   = blockIdx.x & 7;                 // XCD pinning: weights L2-resident
  const int rb0 = (blockIdx.x >> 3) * 64;         // block's first output row
  const int NT  = K >> 5;

  const uint16_t* Ae = A + (size_t)e * a_estride;
  const uint16_t* Be = Bt + (size_t)e * HID * K;

  const int l = tid & 63, wv = tid >> 6;
  const int fr = l & 15, kq = l >> 4;
  const int un = (((fr & 1) << 2) | kq) ^ (fr >> 1);   // phys 16B unit (R12-verified)

  // ---- B staging: thread covers line (tid>>3)+64c, phys unit tid&7 (8 passes) ----
  const int su = (tid & 7) ^ ((tid >> 3) & 7);         // logical unit at this slot
  const uint16_t* pB = Be + (size_t)(2 * (tid >> 3) + (su >> 2)) * K + (su & 3) * 8;
  char* const bdst = lds + tid * 16;

  // ---- A frag global base: lane reads row rb0+mi*16+fr, k = kt*32 + kq*8 ----
  const uint16_t* pA = Ae + (size_t)(rb0 + fr) * K + kq * 8;

  // ---- B frag read offset within slot: + ni*1024 ----
  const int boff = (wv * 64 + (fr >> 1)) * 128 + un * 16;

  f32x4 acc[4][8];
  #pragma unroll
  for (int i = 0; i < 4; ++i)
    #pragma unroll
    for (int j = 0; j < 8; ++j) acc[i][j] = (f32x4)0.0f;

  auto STAGE_B = [&](int kt, int slot) {
    char* db = bdst + slot * 65536;
    const uint16_t* sb = pB + kt * 32;
    #pragma unroll
    for (int c = 0; c < 8; ++c)
      gload16(sb + (size_t)(c * 128) * K, db + c * 8192);
  };

  bf16x8 aC[4], aN[4], bf[8];
  #pragma unroll
  for (int mi = 0; mi < 4; ++mi)
    aC[mi] = *(const bf16x8*)(pA + (size_t)(mi * 16) * K);
  STAGE_B(0, 0);
  asm volatile("s_waitcnt vmcnt(0)");
  __builtin_amdgcn_s_barrier();

  for (int kt = 0; kt < NT; ++kt) {
    const int slot = kt & 1;
    if (kt + 1 < NT) {
      STAGE_B(kt + 1, slot ^ 1);
      #pragma unroll
      for (int mi = 0; mi < 4; ++mi)
        aN[mi] = *(const bf16x8*)(pA + (size_t)(mi * 16) * K + (kt + 1) * 32);
    }
    const char* rbuf = lds + slot * 65536;
    #pragma unroll
    for (int ni = 0; ni < 8; ++ni) bf[ni] = *(const bf16x8*)(rbuf + boff + ni * 1024);
    #pragma unroll
    for (int mi = 0; mi < 4; ++mi)
      #pragma unroll
      for (int ni = 0; ni < 8; ++ni)
        acc[mi][ni] = MF(aC[mi], bf[ni], acc[mi][ni]);
    if (kt + 1 < NT) {
      asm volatile("s_waitcnt vmcnt(0)");      // B-stage + A-prefetch landed
      __builtin_amdgcn_s_barrier();
      #pragma unroll
      for (int mi = 0; mi < 4; ++mi) aC[mi] = aN[mi];
    }
  }

  // ================= fused epilogue =================
  __syncthreads();                              // LDS free for reductions
  float2* red   = (float2*)lds;                 // [8][64] per-wave row partials
  float2* stats = (float2*)(lds + 4096);        // [64] (mu, rs)

  // bias (in f32, pre-LN — matches reference which norms h=xW+b)
  {
    const float* bp = bias + (size_t)e * HID + wv * 128 + fr;
    #pragma unroll
    for (int ni = 0; ni < 8; ++ni) {
      const float bv = bp[ni * 16];
      #pragma unroll
      for (int mi = 0; mi < 4; ++mi)
        #pragma unroll
        for (int i = 0; i < 4; ++i) acc[mi][ni][i] += bv;
    }
  }
  // per-row sum / sumsq: lane-local over ni, shfl over the 16 fr-lanes, LDS over waves
  #pragma unroll
  for (int mi = 0; mi < 4; ++mi)
    #pragma unroll
    for (int i = 0; i < 4; ++i) {
      float s = 0.f, q = 0.f;
      #pragma unroll
      for (int ni = 0; ni < 8; ++ni) { const float v = acc[mi][ni][i]; s += v; q += v * v; }
      #pragma unroll
      for (int m = 1; m < 16; m <<= 1) { s += __shfl_xor(s, m); q += __shfl_xor(q, m); }
      if (fr == 0) red[wv * 64 + mi * 16 + kq * 4 + i] = make_float2(s, q);
    }
  __syncthreads();
  if (tid < 64) {
    float s = 0.f, q = 0.f;
    #pragma unroll
    for (int w = 0; w < 8; ++w) { const float2 t2 = red[w * 64 + tid]; s += t2.x; q += t2.y; }
    const float mu = s * (1.f / HID);
    const float vr = q * (1.f / HID) - mu * mu;
    stats[tid] = make_float2(mu, rsqrtf(vr + LN_EPS));
  }
  __syncthreads();

  const float* gp = g  + (size_t)e * HID + wv * 128 + fr;
  const float* ep = be + (size_t)e * HID + wv * 128 + fr;
  float gv[8], ev[8];
  #pragma unroll
  for (int ni = 0; ni < 8; ++ni) { gv[ni] = gp[ni * 16]; ev[ni] = ep[ni * 16]; }

  if (EPI == 0) {
    // LN + ReLU -> h1n
    uint16_t* Hb = H + ((size_t)e * CBrows + rb0) * HID + wv * 128 + fr;
    #pragma unroll
    for (int mi = 0; mi < 4; ++mi)
      #pragma unroll
      for (int i = 0; i < 4; ++i) {
        const int r = mi * 16 + kq * 4 + i;
        const float2 st = stats[r];
        uint16_t* hp = Hb + (size_t)r * HID;
        #pragma unroll
        for (int ni = 0; ni < 8; ++ni) {
          const float v = (acc[mi][ni][i] - st.x) * st.y * gv[ni] + ev[ni];
          hp[ni * 16] = f2bf(fmaxf(v, 0.f));
        }
      }
  } else {
    // LN + ReLU + dot(W3) -> qs  (h2 never materialized)
    const float* wp = W3 + (size_t)e * HID + wv * 128 + fr;
    float w3v[8];
    #pragma unroll
    for (int ni = 0; ni < 8; ++ni) w3v[ni] = wp[ni * 16];
    float* redf = (float*)red;                 // [8][64] dot partials (post-stats reuse)
    #pragma unroll
    for (int mi = 0; mi < 4; ++mi)
      #pragma unroll
      for (int i = 0; i < 4; ++i) {
        const int r = mi * 16 + kq * 4 + i;
        const float2 st = stats[r];
        float d = 0.f;
        #pragma unroll
        for (int ni = 0; ni < 8; ++ni) {
          const float v = fmaxf((acc[mi][ni][i] - st.x) * st.y * gv[ni] + ev[ni], 0.f);
          d += v * w3v[ni];
        }
        #pragma unroll
        for (int m = 1; m < 16; m <<= 1) d += __shfl_xor(d, m);
        if (fr == 0) redf[wv * 64 + r] = d;
      }
    __syncthreads();
    if (tid < 64) {
      float d = 0.f;
      #pragma unroll
      for (int w = 0; w < 8; ++w) d += redf[w * 64 + tid];
      out[BATCH + (size_t)e * BATCH + b0 + rb0 + tid] = d + b3[e];   // qs
    }
  }
}

// ---------------- q[b] = min_e qs[e][b] ----------------
__global__ __launch_bounds__(256) void min_q(float* __restrict__ out) {
  const int b = blockIdx.x * 256 + threadIdx.x;
  float m = out[BATCH + b];
  #pragma unroll
  for (int e = 1; e < EN; ++e) m = fminf(m, out[BATCH + (size_t)e * BATCH + b]);
  out[b] = m;
}

extern "C" void kernel_launch(void* const* d_in, const int* in_sizes, int n_in,
                              void* d_out, int out_size, void* d_ws, size_t ws_size,
                              hipStream_t stream) {
  const float* x   = (const float*)d_in[0];
  const float* W1  = (const float*)d_in[1];
  const float* b1  = (const float*)d_in[2];
  const float* g1  = (const float*)d_in[3];
  const float* be1 = (const float*)d_in[4];
  const float* W2  = (const float*)d_in[5];
  const float* b2  = (const float*)d_in[6];
  const float* g2  = (const float*)d_in[7];
  const float* be2 = (const float*)d_in[8];
  const float* W3  = (const float*)d_in[9];
  const float* b3  = (const float*)d_in[10];
  float* out = (float*)d_out;

  // ---- fixed workspace region: converted inputs (40 MB) ----
  char* ws = (char*)d_ws;
  uint16_t* xb  = (uint16_t*)ws; ws += (size_t)BATCH * DIN * 2;      // 16 MB
  uint16_t* w1t = (uint16_t*)ws; ws += (size_t)EN * DIN * HID * 2;   // 8 MB
  uint16_t* w2t = (uint16_t*)ws; ws += (size_t)EN * HID * HID * 2;   // 16 MB
  size_t fixed = (size_t)(ws - (char*)d_ws);

  // ---- batch-chunk size CB (power of 2, >=64): only h1 now (16 KB/row) ----
  size_t avail = (ws_size > fixed) ? (ws_size - fixed) : 0;
  const size_t per_row = (size_t)EN * HID * 2ULL;    // h1 bytes per batch row
  int CB = BATCH;
  while (CB > 64 && (size_t)CB * per_row > avail) CB >>= 1;
  const int nchunks = BATCH / CB;
  uint16_t* h1 = (uint16_t*)ws;

  // ---- one-time conversions ----
  cvt_bf16<<<(BATCH * DIN / 4 + 255) / 256, 256, 0, stream>>>(x, xb, (long)BATCH * DIN);
  transpose_cvt<<<dim3(HID / 32, DIN / 32, EN), 256, 0, stream>>>(W1, w1t, DIN, HID);
  transpose_cvt<<<dim3(HID / 32, HID / 32, EN), 256, 0, stream>>>(W2, w2t, HID, HID);

  const int gblocks = (CB / 64) * EN;
  for (int c = 0; c < nchunks; ++c) {
    const int b0 = c * CB;
    gemm_fused<0><<<gblocks, 512, 0, stream>>>(
        xb + (size_t)b0 * DIN, (size_t)0, w1t, b1, g1, be1,
        nullptr, nullptr, h1, nullptr, CB, b0, DIN);
    gemm_fused<1><<<gblocks, 512, 0, stream>>>(
        h1, (size_t)CB * HID, w2t, b2, g2, be2,
        W3, b3, nullptr, out, CB, b0, HID);
  }
  min_q<<<BATCH / 256, 256, 0, stream>>>(out);
}

// Round 14
// 659.645 us; speedup vs baseline: 1.5950x; 1.5950x over previous
//
#include <hip/hip_runtime.h>
#include <hip/hip_bf16.h>
#include <stdint.h>

#define EN    8
#define DIN   512
#define HID   1024
#define BATCH 16384
#define LN_EPS 1e-5f

typedef __bf16   bf16x8 __attribute__((ext_vector_type(8)));
typedef float    f32x4  __attribute__((ext_vector_type(4)));
typedef uint16_t u16x8  __attribute__((ext_vector_type(8)));
typedef uint16_t u16x4  __attribute__((ext_vector_type(4)));
typedef float    fl4    __attribute__((ext_vector_type(4)));

__device__ __forceinline__ uint16_t f2bf(float f) {
  uint32_t x = __builtin_bit_cast(uint32_t, f);
  uint32_t r = (x + 0x7fffu + ((x >> 16) & 1u)) >> 16;  // RNE
  return (uint16_t)r;
}
__device__ __forceinline__ float bf2f(uint16_t u) {
  return __builtin_bit_cast(float, (uint32_t)u << 16);
}

__device__ __forceinline__ void gload16(const uint16_t* g, char* lds_d) {
  __builtin_amdgcn_global_load_lds(
      (const __attribute__((address_space(1))) uint32_t*)g,
      (__attribute__((address_space(3))) uint32_t*)lds_d, 16, 0, 0);
}

__device__ __forceinline__ f32x4 MF(bf16x8 a, bf16x8 b, f32x4 c) {
  return __builtin_amdgcn_mfma_f32_16x16x32_bf16(a, b, c, 0, 0, 0);
}

#define SB0() __builtin_amdgcn_sched_barrier(0)

// ---------------- conversion: fp32 -> bf16 ----------------
__global__ __launch_bounds__(256) void cvt_bf16(const float* __restrict__ src,
                                                uint16_t* __restrict__ dst, long n) {
  long i = ((long)blockIdx.x * 256 + threadIdx.x) * 4;
  if (i >= n) return;
  fl4 v = *(const fl4*)(src + i);
  u16x4 o;
  #pragma unroll
  for (int j = 0; j < 4; ++j) o[j] = f2bf(v[j]);
  *(u16x4*)(dst + i) = o;
}

// ---------------- transpose + convert: [E][R][C] fp32 -> [E][C][R] bf16 ----------------
__global__ __launch_bounds__(256) void transpose_cvt(const float* __restrict__ src,
                                                     uint16_t* __restrict__ dst,
                                                     int R, int C) {
  __shared__ float tile[32][33];
  const int e = blockIdx.z;
  const int c0 = blockIdx.x * 32;
  const int r0 = blockIdx.y * 32;
  const int tx = threadIdx.x & 31, ty = threadIdx.x >> 5;
  const float* s = src + (size_t)e * R * C;
  uint16_t*    d = dst + (size_t)e * R * C;
  #pragma unroll
  for (int i = 0; i < 32; i += 8)
    tile[ty + i][tx] = s[(size_t)(r0 + ty + i) * C + (c0 + tx)];
  __syncthreads();
  #pragma unroll
  for (int i = 0; i < 32; i += 8)
    d[(size_t)(c0 + ty + i) * R + (r0 + tx)] = f2bf(tile[tx][ty + i]);
}

// ====== 256x256 GEMM, 4 waves, 128x128 wave tile, register-dbuf fragments ======
// C[e][M][HID] = A[e][M][K] * Bt[e][HID][K]^T + bias.  256 thr = 4 waves (2M x 2N).
// BK=64.  LDS 128 KiB = 2 dbuf x (A 256x128B + B 256x128B).  128B rows, 16B unit u
// at phys u ^ (row&7) (proven 0-conflict).  Empirical best of 8 structural
// variants (R3-R13): 77us/dispatch, total 659.9us.
__global__ __launch_bounds__(256, 1) void gemm4w(
    const uint16_t* __restrict__ A, size_t a_estride,
    const uint16_t* __restrict__ Bt,
    const float*    __restrict__ bias,
    uint16_t*       __restrict__ C,
    int M, int K) {
  __shared__ __attribute__((aligned(16))) char lds[131072];
  const int tid = threadIdx.x;
  const int bx  = blockIdx.x;
  const int e   = bx & 7;            // member -> XCD pinning
  const int t   = bx >> 3;
  const int mt  = t >> 2;            // nt inner: neighbors share A panel
  const int nt  = t & 3;
  const int NT  = K >> 6;            // K-tiles of 64

  const uint16_t* Ae = A + (size_t)e * a_estride + (size_t)(mt * 256) * K;
  const uint16_t* Be = Bt + ((size_t)e * HID + nt * 256) * K;

  const int l  = tid & 63, wid = tid >> 6;
  const int wr = wid >> 1, wc = wid & 1;        // 2 x 2 waves, tile 128x128
  const int fr = l & 15, kq = l >> 4, f7 = fr & 7;

  // staging: lane covers row (wid*8 + l>>3) (+j*32), phys unit l&7, logical su
  const int r8 = l >> 3;
  const int su = (l & 7) ^ r8;
  const uint16_t* pA = Ae + (size_t)(wid * 8 + r8) * K + su * 8;
  const uint16_t* pB = Be + (size_t)(wid * 8 + r8) * K + su * 8;
  char* const dst0 = lds + tid * 16;

  // frag read byte offsets (within dbuf): +mi*2048; kh1 = ^64
  const int rdA0 = (wr * 128 + fr) * 128 + ((kq ^ f7) << 4);
  const int rdB0 = 32768 + (wc * 128 + fr) * 128 + ((kq ^ f7) << 4);

  f32x4 acc[8][8];
  #pragma unroll
  for (int i = 0; i < 8; ++i)
    #pragma unroll
    for (int j = 0; j < 8; ++j) acc[i][j] = (f32x4)0.0f;

  auto STAGE = [&](int kt) {
    char* db = dst0 + ((kt & 1) << 16);
    const uint16_t* sa = pA + kt * 64;
    const uint16_t* sb = pB + kt * 64;
    #pragma unroll
    for (int j = 0; j < 8; ++j) gload16(sa + (size_t)(j * 32) * K, db + j * 4096);
    #pragma unroll
    for (int j = 0; j < 8; ++j) gload16(sb + (size_t)(j * 32) * K, db + 32768 + j * 4096);
  };

  // prologue
  STAGE(0);
  asm volatile("s_waitcnt vmcnt(0)");
  SB0();
  __builtin_amdgcn_s_barrier();
  SB0();

  bf16x8 a0[8], b0[8], a1[8], b1[8];
  {
    const char* rb = lds;
    #pragma unroll
    for (int i = 0; i < 8; ++i) {
      a0[i] = *(const bf16x8*)(rb + rdA0 + i * 2048);
      b0[i] = *(const bf16x8*)(rb + rdB0 + i * 2048);
    }
  }

  for (int kt = 0; kt < NT; ++kt) {
    const char* rb = lds + ((kt & 1) << 16);
    const char* rq = lds + (((kt + 1) & 1) << 16);
    if (kt + 1 < NT) STAGE(kt + 1);            // 16 gload_lds, lands during this kt
    // ---- kh0: 64 MFMA; kh1 frag reads issued ahead of each burst ----
    #pragma unroll
    for (int mi = 0; mi < 8; ++mi) {
      a1[mi] = *(const bf16x8*)(rb + ((rdA0 + mi * 2048) ^ 64));
      b1[mi] = *(const bf16x8*)(rb + ((rdB0 + mi * 2048) ^ 64));
      __builtin_amdgcn_s_setprio(1);
      #pragma unroll
      for (int ni = 0; ni < 8; ++ni)
        acc[mi][ni] = MF(a0[mi], b0[ni], acc[mi][ni]);
      __builtin_amdgcn_s_setprio(0);
    }
    // ---- kh1: 64 MFMA ----
    #pragma unroll
    for (int mi = 0; mi < 8; ++mi) {
      __builtin_amdgcn_s_setprio(1);
      #pragma unroll
      for (int ni = 0; ni < 8; ++ni)
        acc[mi][ni] = MF(a1[mi], b1[ni], acc[mi][ni]);
      __builtin_amdgcn_s_setprio(0);
    }
    if (kt + 1 < NT) {
      asm volatile("s_waitcnt vmcnt(0)");       // stage(kt+1) landed (issued ~2500 cyc ago)
      SB0();
      __builtin_amdgcn_s_barrier();             // publish to all waves; WAR separation
      SB0();
      #pragma unroll
      for (int i = 0; i < 8; ++i) {             // next tile kh0 frags
        a0[i] = *(const bf16x8*)(rq + rdA0 + i * 2048);
        b0[i] = *(const bf16x8*)(rq + rdB0 + i * 2048);
      }
    }
  }

  // epilogue: bias + direct bf16 store.  D map: col=l&15, row=(l>>4)*4+i [m89]
  const int col0 = nt * 256 + wc * 128 + fr;
  const int row0 = mt * 256 + wr * 128 + kq * 4;
  float bv[8];
  #pragma unroll
  for (int ni = 0; ni < 8; ++ni) bv[ni] = bias[(size_t)e * HID + col0 + ni * 16];
  #pragma unroll
  for (int mi = 0; mi < 8; ++mi) {
    #pragma unroll
    for (int i = 0; i < 4; ++i) {
      const int rg = row0 + mi * 16 + i;
      uint16_t* cp = C + ((size_t)e * M + rg) * HID + col0;
      #pragma unroll
      for (int ni = 0; ni < 8; ++ni)
        cp[ni * 16] = f2bf(acc[mi][ni][i] + bv[ni]);
    }
  }
}

// ---------------- LayerNorm + ReLU, in place on bf16 [E*CB][HID] ----------------
__global__ __launch_bounds__(256) void ln_relu(uint16_t* __restrict__ h,
                                               const float* __restrict__ g,
                                               const float* __restrict__ be,
                                               int kshift) {        // e = row >> kshift
  const int wid = threadIdx.x >> 6, l = threadIdx.x & 63;
  const long row = (long)blockIdx.x * 4 + wid;
  const int e = (int)(row >> kshift);
  uint16_t* p = h + row * HID;

  u16x8 s0 = *(const u16x8*)(p + l * 8);
  u16x8 s1 = *(const u16x8*)(p + 512 + l * 8);
  float v[16];
  #pragma unroll
  for (int j = 0; j < 8; ++j) { v[j] = bf2f(s0[j]); v[8 + j] = bf2f(s1[j]); }

  float sum = 0.f, sq = 0.f;
  #pragma unroll
  for (int j = 0; j < 16; ++j) { sum += v[j]; sq += v[j] * v[j]; }
  #pragma unroll
  for (int m = 1; m < 64; m <<= 1) {
    sum += __shfl_xor(sum, m);
    sq  += __shfl_xor(sq, m);
  }
  const float mu  = sum * (1.0f / HID);
  const float var = sq * (1.0f / HID) - mu * mu;
  const float rs  = rsqrtf(var + LN_EPS);

  const float* gp = g  + (size_t)e * HID;
  const float* bp = be + (size_t)e * HID;
  u16x8 o0, o1;
  #pragma unroll
  for (int j = 0; j < 8; ++j) {
    const int c0 = l * 8 + j, c1 = 512 + l * 8 + j;
    float x0 = (v[j]     - mu) * rs * gp[c0] + bp[c0];
    float x1 = (v[8 + j] - mu) * rs * gp[c1] + bp[c1];
    o0[j] = f2bf(fmaxf(x0, 0.f));
    o1[j] = f2bf(fmaxf(x1, 0.f));
  }
  *(u16x8*)(p + l * 8) = o0;
  *(u16x8*)(p + 512 + l * 8) = o1;
}

// ------- fused LN2 + ReLU + head dot + min: reads pre-LN h2, writes q/qs only -------
__global__ __launch_bounds__(256) void ln_head(const uint16_t* __restrict__ h,
                                               const float* __restrict__ g,
                                               const float* __restrict__ be,
                                               const float* __restrict__ W3,
                                               const float* __restrict__ b3,
                                               float* __restrict__ out,
                                               int b0, int CB) {
  __shared__ float qsh[EN];
  const int wv = threadIdx.x >> 6, l = threadIdx.x & 63;
  const long b = blockIdx.x;
  #pragma unroll
  for (int ee = 0; ee < 2; ++ee) {
    const int e = wv + ee * 4;
    const uint16_t* p = h + ((size_t)e * CB + b) * HID;
    u16x8 s0 = *(const u16x8*)(p + l * 8);
    u16x8 s1 = *(const u16x8*)(p + 512 + l * 8);
    float v[16];
    #pragma unroll
    for (int j = 0; j < 8; ++j) { v[j] = bf2f(s0[j]); v[8 + j] = bf2f(s1[j]); }
    float sum = 0.f, sq = 0.f;
    #pragma unroll
    for (int j = 0; j < 16; ++j) { sum += v[j]; sq += v[j] * v[j]; }
    #pragma unroll
    for (int m = 1; m < 64; m <<= 1) {
      sum += __shfl_xor(sum, m);
      sq  += __shfl_xor(sq, m);
    }
    const float mu  = sum * (1.0f / HID);
    const float var = sq * (1.0f / HID) - mu * mu;
    const float rs  = rsqrtf(var + LN_EPS);
    const float* gp = g  + (size_t)e * HID;
    const float* bp = be + (size_t)e * HID;
    const float* w  = W3 + (size_t)e * HID;
    float dot = 0.f;
    #pragma unroll
    for (int j = 0; j < 8; ++j) {
      const int c0 = l * 8 + j, c1 = 512 + l * 8 + j;
      float x0 = fmaxf((v[j]     - mu) * rs * gp[c0] + bp[c0], 0.f);
      float x1 = fmaxf((v[8 + j] - mu) * rs * gp[c1] + bp[c1], 0.f);
      dot += x0 * w[c0] + x1 * w[c1];
    }
    #pragma unroll
    for (int m = 1; m < 64; m <<= 1) dot += __shfl_xor(dot, m);
    if (l == 0) {
      const float qe = dot + b3[e];
      qsh[e] = qe;
      out[BATCH + (size_t)e * BATCH + b0 + b] = qe;   // qs
    }
  }
  __syncthreads();
  if (threadIdx.x == 0) {
    float m = qsh[0];
    #pragma unroll
    for (int i = 1; i < EN; ++i) m = fminf(m, qsh[i]);
    out[b0 + b] = m;                                   // q
  }
}

extern "C" void kernel_launch(void* const* d_in, const int* in_sizes, int n_in,
                              void* d_out, int out_size, void* d_ws, size_t ws_size,
                              hipStream_t stream) {
  const float* x   = (const float*)d_in[0];
  const float* W1  = (const float*)d_in[1];
  const float* b1  = (const float*)d_in[2];
  const float* g1  = (const float*)d_in[3];
  const float* be1 = (const float*)d_in[4];
  const float* W2  = (const float*)d_in[5];
  const float* b2  = (const float*)d_in[6];
  const float* g2  = (const float*)d_in[7];
  const float* be2 = (const float*)d_in[8];
  const float* W3  = (const float*)d_in[9];
  const float* b3  = (const float*)d_in[10];
  float* out = (float*)d_out;

  // ---- fixed workspace region: converted inputs (40 MB) ----
  char* ws = (char*)d_ws;
  uint16_t* xb  = (uint16_t*)ws; ws += (size_t)BATCH * DIN * 2;      // 16 MB
  uint16_t* w1t = (uint16_t*)ws; ws += (size_t)EN * DIN * HID * 2;   // 8 MB
  uint16_t* w2t = (uint16_t*)ws; ws += (size_t)EN * HID * HID * 2;   // 16 MB
  size_t fixed = (size_t)(ws - (char*)d_ws);

  // ---- batch-chunk size CB (power of 2, >=256) so h1+h2 fit in workspace ----
  size_t avail = (ws_size > fixed) ? (ws_size - fixed) : 0;
  const size_t per_row = 2ULL * EN * HID * 2ULL;   // h1+h2 bytes per batch row
  int CB = BATCH;
  while (CB > 256 && (size_t)CB * per_row > avail) CB >>= 1;
  const int nchunks = BATCH / CB;
  const int kshift = __builtin_ctz(CB);

  uint16_t* h1 = (uint16_t*)ws; ws += (size_t)EN * CB * HID * 2;
  uint16_t* h2 = (uint16_t*)ws;

  // ---- one-time conversions ----
  cvt_bf16<<<(BATCH * DIN / 4 + 255) / 256, 256, 0, stream>>>(x, xb, (long)BATCH * DIN);
  transpose_cvt<<<dim3(HID / 32, DIN / 32, EN), 256, 0, stream>>>(W1, w1t, DIN, HID);
  transpose_cvt<<<dim3(HID / 32, HID / 32, EN), 256, 0, stream>>>(W2, w2t, HID, HID);

  const int gblocks = (CB / 256) * (HID / 256) * EN;

  for (int c = 0; c < nchunks; ++c) {
    const int b0 = c * CB;
    gemm4w<<<gblocks, 256, 0, stream>>>(xb + (size_t)b0 * DIN, (size_t)0,
                                        w1t, b1, h1, CB, DIN);
    ln_relu<<<(EN * CB) / 4, 256, 0, stream>>>(h1, g1, be1, kshift);
    gemm4w<<<gblocks, 256, 0, stream>>>(h1, (size_t)CB * HID,
                                        w2t, b2, h2, CB, HID);
    ln_head<<<CB, 256, 0, stream>>>(h2, g2, be2, W3, b3, out, b0, CB);
  }
}